// Round 14
// baseline (79.797 us; speedup 1.0000x reference)
//
#include <hip/hip_runtime.h>
#include <hip/hip_bf16.h>

#define NEG_SLOPE 0.2f
#define CAP 5120          // per-bucket capacity (avg 4096, ~16-sigma margin)
#define CHUNK 4096        // edges per workgroup in bfill path
#define LOG2E 1.4426950408889634f

typedef __attribute__((ext_vector_type(8))) short short8v;
typedef __attribute__((ext_vector_type(4))) short short4v;
typedef __attribute__((ext_vector_type(4))) float f32x4;
typedef _Float16 __attribute__((ext_vector_type(8))) h8;
typedef _Float16 __attribute__((ext_vector_type(2))) h2;

__device__ __forceinline__ short f2bf(float f) {
  __hip_bfloat16 b = __float2bfloat16(f);  // RNE
  return *reinterpret_cast<short*>(&b);
}

// f16x8 dot f16x8 accumulated into f32 via v_dot2_f32_f16 (4 instrs).
__device__ __forceinline__ float dot8f(h8 a, h8 b, float c) {
#if __has_builtin(__builtin_amdgcn_fdot2)
  c = __builtin_amdgcn_fdot2(__builtin_shufflevector(a, a, 0, 1),
                             __builtin_shufflevector(b, b, 0, 1), c, false);
  c = __builtin_amdgcn_fdot2(__builtin_shufflevector(a, a, 2, 3),
                             __builtin_shufflevector(b, b, 2, 3), c, false);
  c = __builtin_amdgcn_fdot2(__builtin_shufflevector(a, a, 4, 5),
                             __builtin_shufflevector(b, b, 4, 5), c, false);
  c = __builtin_amdgcn_fdot2(__builtin_shufflevector(a, a, 6, 7),
                             __builtin_shufflevector(b, b, 6, 7), c, false);
#else
#pragma unroll
  for (int i = 0; i < 8; ++i) c += (float)a[i] * (float)b[i];
#endif
  return c;
}

// packed leakyrelu: max(h, 0.2h) elementwise (v_pk_mul + v_pk_max)
__device__ __forceinline__ h8 leaky8(h8 hs) {
  h8 hl = hs * (_Float16)NEG_SLOPE;
  return __builtin_elementwise_max(hs, hl);
}

__device__ __forceinline__ h8 shfl_xor_h8(h8 v, int off) {
  int4 i = *(int4*)&v;
  i.x = __shfl_xor(i.x, off);
  i.y = __shfl_xor(i.y, off);
  i.z = __shfl_xor(i.z, off);
  i.w = __shfl_xor(i.w, off);
  return *(h8*)&i;
}

// 8-lane sum reduction in the VALU pipe via DPP.
__device__ __forceinline__ float row_reduce8(float p) {
  p += __int_as_float(__builtin_amdgcn_update_dpp(
      0, __float_as_int(p), 0xB1, 0xF, 0xF, true));   // quad_perm [1,0,3,2]
  p += __int_as_float(__builtin_amdgcn_update_dpp(
      0, __float_as_int(p), 0x4E, 0xF, 0xF, true));   // quad_perm [2,3,0,1]
  p += __int_as_float(__builtin_amdgcn_update_dpp(
      0, __float_as_int(p), 0x141, 0xF, 0xF, true));  // row_half_mirror
  return p;
}

// K1 fused: blocks [0,nbf) = bucketed edge fill; blocks [nbf,..) = LDS-staged
// MFMA transform reading x / Wl / Wr / bl / br (f32) directly — weight rows
// are L2-hot (64 KB total); in-register f32->bf16 keeps bits identical to the
// old k_prep path. Outputs f16 xlh / xrh.
__global__ __launch_bounds__(256) void k_tbf(
    const float* __restrict__ x, const float* __restrict__ Wl,
    const float* __restrict__ Wr, const float* __restrict__ bl,
    const float* __restrict__ br, const int* __restrict__ eidx,
    int* __restrict__ bcur, unsigned* __restrict__ pk,
    _Float16* __restrict__ xlh, _Float16* __restrict__ xrh, int nN, int E_,
    int nbf) {
  __shared__ union {
    struct { int hist[256]; int base[256]; } bf;
    short xs[64 * 136];
  } u;
  const int t = threadIdx.x;

  if (blockIdx.x < nbf) {
    // ---------------- bfill path ----------------
    u.bf.hist[t] = 0;
    __syncthreads();
    const int e0 = blockIdx.x * CHUNK + t * 16;
    unsigned mypk[16];
    int myrank[16];
    const bool valid = (e0 < E_);  // E_ % 16 == 0 -> all-or-nothing per thread
    if (valid) {
      const int4* ps = (const int4*)(eidx + e0);
      const int4* pd = (const int4*)(eidx + E_ + e0);
#pragma unroll
      for (int j = 0; j < 4; ++j) {
        int4 sv = ps[j];
        int4 dv = pd[j];
        int ss[4] = {sv.x, sv.y, sv.z, sv.w};
        int dd[4] = {dv.x, dv.y, dv.z, dv.w};
#pragma unroll
        for (int q = 0; q < 4; ++q) {
          unsigned p = ((unsigned)dd[q] << 16) | (unsigned)ss[q];
          mypk[j * 4 + q] = p;
          myrank[j * 4 + q] = atomicAdd(&u.bf.hist[dd[q] >> 8], 1);
        }
      }
    }
    __syncthreads();
    u.bf.base[t] = u.bf.hist[t] ? atomicAdd(&bcur[t], u.bf.hist[t]) : 0;
    __syncthreads();
    if (valid) {
#pragma unroll
      for (int j = 0; j < 16; ++j) {
        int b = mypk[j] >> 24;
        unsigned idx = (unsigned)(u.bf.base[b] + myrank[j]);
        if (idx < CAP) pk[(unsigned)b * CAP + idx] = mypk[j];
      }
    }
    return;
  }

  // ---------------- transform path ----------------
  const int n0 = (blockIdx.x - nbf) * 64;
#pragma unroll
  for (int i = 0; i < 8; ++i) {
    int f = (i * 256 + t) * 4;        // flat f32 index into 64x128 tile
    int node = f >> 7, k = f & 127;
    int gn = min(n0 + node, nN - 1);
    float4 v = *(const float4*)(x + (size_t)gn * 128 + k);
    short4v s4;
    s4[0] = f2bf(v.x); s4[1] = f2bf(v.y); s4[2] = f2bf(v.z); s4[3] = f2bf(v.w);
    *(short4v*)(u.xs + node * 136 + k) = s4;
  }
  __syncthreads();

  const int w = t >> 6;
  const int lane = t & 63;
  const int r = lane & 15;
  const int kb = lane >> 4;

  short8v bfr[2][4];
#pragma unroll
  for (int c = 0; c < 2; ++c) {
    const int ch = (w * 2 + c) * 16 + r;
    const float* wrow = ((ch < 64) ? (Wl + (size_t)ch * 128)
                                   : (Wr + (size_t)(ch - 64) * 128)) + kb * 8;
#pragma unroll
    for (int kk = 0; kk < 4; ++kk) {
      float4 w0 = *(const float4*)(wrow + kk * 32);
      float4 w1 = *(const float4*)(wrow + kk * 32 + 4);
      short8v b;
      b[0] = f2bf(w0.x); b[1] = f2bf(w0.y); b[2] = f2bf(w0.z); b[3] = f2bf(w0.w);
      b[4] = f2bf(w1.x); b[5] = f2bf(w1.y); b[6] = f2bf(w1.z); b[7] = f2bf(w1.w);
      bfr[c][kk] = b;
    }
  }

  f32x4 acc[4][2];
#pragma unroll
  for (int nt = 0; nt < 4; ++nt)
#pragma unroll
    for (int c = 0; c < 2; ++c) acc[nt][c] = (f32x4){0.f, 0.f, 0.f, 0.f};

#pragma unroll
  for (int nt = 0; nt < 4; ++nt) {
    short8v afr[4];
#pragma unroll
    for (int kk = 0; kk < 4; ++kk)
      afr[kk] =
          *(const short8v*)(u.xs + (nt * 16 + r) * 136 + kb * 8 + kk * 32);
#pragma unroll
    for (int kk = 0; kk < 4; ++kk) {
      acc[nt][0] =
          __builtin_amdgcn_mfma_f32_16x16x32_bf16(afr[kk], bfr[0][kk],
                                                  acc[nt][0], 0, 0, 0);
      acc[nt][1] =
          __builtin_amdgcn_mfma_f32_16x16x32_bf16(afr[kk], bfr[1][kk],
                                                  acc[nt][1], 0, 0, 0);
    }
  }

#pragma unroll
  for (int c = 0; c < 2; ++c) {
    const int ch = (w * 2 + c) * 16 + r;
    const float bv = (ch < 64) ? bl[ch] : br[ch - 64];
#pragma unroll
    for (int nt = 0; nt < 4; ++nt) {
#pragma unroll
      for (int i = 0; i < 4; ++i) {
        int node = n0 + nt * 16 + kb * 4 + i;
        if (node < nN) {
          float v = acc[nt][c][i] + bv;
          if (ch < 64) xlh[(size_t)node * 64 + ch] = (_Float16)v;
          else         xrh[(size_t)node * 64 + (ch - 64)] = (_Float16)v;
        }
      }
    }
  }
}

// K2: per-bucket finalize: node histogram -> scan -> rowlo/rowhi -> 2B csr,
// plus degree-balanced node pairing (nperm) so each k_node wave's two halves
// get near-equal edge counts (kills the max(deg0,deg1) imbalance waste).
__global__ __launch_bounds__(256) void k_nfill(
    const unsigned* __restrict__ pk, const int* __restrict__ bcur,
    int* __restrict__ rowlo, int* __restrict__ rowhi,
    unsigned short* __restrict__ csr, unsigned* __restrict__ nperm, int nN) {
  __shared__ int hist[256];
  __shared__ int nbase[256];
  __shared__ int wsum[4];
  __shared__ int keys[256];
  __shared__ int sortedi[256];
  const int b = blockIdx.x;
  const int t = threadIdx.x;
  const int nb0 = b << 8;
  const int cnt = min(bcur[b], CAP);
  const int cntN = min(256, nN - nb0);    // nodes in this bucket
  const unsigned gbase = (unsigned)b * CAP;
  hist[t] = 0;
  __syncthreads();
  for (int i = t; i < cnt; i += 256)
    atomicAdd(&hist[(pk[gbase + i] >> 16) & 255], 1);
  __syncthreads();
  const int lane = t & 63;
  const int wid = t >> 6;
  int v = hist[t];
  const int orig = v;   // this node's degree
#pragma unroll
  for (int off = 1; off < 64; off <<= 1) {
    int uu = __shfl_up(v, off);
    if (lane >= off) v += uu;
  }
  if (lane == 63) wsum[wid] = v;
  __syncthreads();
  int add = 0;
  for (int ww = 0; ww < wid; ++ww) add += wsum[ww];
  const int excl = v - orig + add;
  nbase[t] = excl;
  if (t < cntN) {
    rowlo[nb0 + t] = (int)gbase + excl;
    rowhi[nb0 + t] = (int)gbase + excl + orig;
  }
  __syncthreads();
  hist[t] = 0;  // reuse as cursor
  // degree-rank pairing: unique keys (deg<<8)|t, descending rank via
  // wave-uniform LDS broadcast scan (256 iter, ~1 cyc each)
  keys[t] = ((t < cntN ? orig : -1) << 8) | t;
  __syncthreads();
  {
    const int mykey = keys[t];
    int rank = 0;
    for (int i = 0; i < 256; ++i) rank += (keys[i] > mykey);
    sortedi[rank] = t;
  }
  // phase 3: scatter src (2B) into node segments
  for (int i = t; i < cnt; i += 256) {
    unsigned p = pk[gbase + i];
    int dl = (p >> 16) & 255;
    int slot = nbase[dl] + atomicAdd(&hist[dl], 1);
    csr[gbase + slot] = (unsigned short)(p & 0xFFFFu);
  }
  __syncthreads();
  if (t < 128) {
    int loc0 = sortedi[2 * t], loc1 = sortedi[2 * t + 1];
    unsigned pr;
    if (loc0 >= cntN) pr = 0xFFFFFFFFu;  // whole pair dead
    else pr = ((unsigned)loc0 << 16) |
              (loc1 < cntN ? (unsigned)loc1 : 0xFFFFu);
    nperm[b * 128 + t] = pr;
  }
}

// K3: fused per-node online softmax, f16 packed datapath. TWO nodes per wave
// (degree-matched via nperm); per node 4 subgroups x 8 lanes; lane r owns
// ch 8r..8r+7. m uniform per half; defer-max fast path (sc == 1 exactly);
// 4-deep gather pipeline.
__global__ __launch_bounds__(256) void k_node(
    const unsigned* __restrict__ nperm, const int* __restrict__ rowlo,
    const int* __restrict__ rowhi, const unsigned short* __restrict__ csr,
    const _Float16* __restrict__ xlh, const _Float16* __restrict__ xrh,
    const float* __restrict__ att, const float* __restrict__ bias,
    float* __restrict__ out, int nN) {
  const int wvid = (blockIdx.x * 256 + threadIdx.x) >> 6;  // wave id
  const unsigned pr = nperm[wvid];
  if (pr == 0xFFFFFFFFu) return;
  const int lane = threadIdx.x & 63;
  const int h = lane >> 5;          // node half 0/1
  const int g = (lane >> 3) & 3;    // subgroup within half, 0..3
  const int r = lane & 7;           // channel block: ch 8r..8r+7
  const unsigned loc = h ? (pr & 0xFFFFu) : (pr >> 16);
  const bool live = (loc != 0xFFFFu);
  const int d = ((wvid >> 7) << 8) + (live ? (int)loc : 0);

  h8 at8;
#pragma unroll
  for (int i = 0; i < 8; ++i) at8[i] = (_Float16)att[r * 8 + i];

  const h8 xr8 = *(const h8*)(xrh + (size_t)d * 64 + r * 8);
  const h8 sv8 = *(const h8*)(xlh + (size_t)d * 64 + r * 8);

  // self-loop logit (identical across the half's 4 subgroups)
  float ps = dot8f(leaky8(sv8 + xr8), at8, 0.f);
  ps = row_reduce8(ps) * LOG2E;

  const bool g0 = (g == 0);
  float m = ps;                 // uniform per half by construction
  float ssum = g0 ? 1.f : 0.f;
  h8 acc = g0 ? sv8 : (h8){0, 0, 0, 0, 0, 0, 0, 0};

  const int lo = live ? rowlo[d] : 0;
  const int hi = live ? rowhi[d] : 0;
  const int nst = (hi - lo + 3) >> 2;   // rounds of 4 edges per node

#define PROC(VREG, SIDX)                                                      \
  {                                                                           \
    const bool act = ((SIDX) < hi);                                           \
    float p = dot8f(leaky8(VREG + xr8), at8, 0.f);                            \
    p = row_reduce8(p);                                                       \
    const float pm = act ? p * LOG2E : -3.0e38f;                              \
    if (__any(pm > m)) {  /* new max somewhere in the wave */                 \
      float q = pm;                                                           \
      q = fmaxf(q, __shfl_xor(q, 8));                                         \
      q = fmaxf(q, __shfl_xor(q, 16));  /* half-wide max */                   \
      const float nm = fmaxf(m, q);     /* uniform per half */                \
      const float sc = exp2f(m - nm);                                         \
      const float w = exp2f(pm - nm);                                         \
      ssum = fmaf(ssum, sc, w);                                               \
      acc = acc * (_Float16)sc + VREG * (_Float16)w;                          \
      m = nm;                                                                 \
    } else {              /* fast path: sc == 1 exactly */                    \
      const float w = exp2f(pm - m);                                          \
      ssum += w;                                                              \
      acc += VREG * (_Float16)w;                                              \
    }                                                                         \
  }

  int sA = lo + g, sB = sA + 4, sC = sA + 8, sD = sA + 12;
  h8 vA, vB, vC, vD;
  {
    int srcA = (sA < hi) ? (int)csr[sA] : d;
    vA = *(const h8*)(xlh + (size_t)srcA * 64 + r * 8);
    int srcB = (sB < hi) ? (int)csr[sB] : d;
    vB = *(const h8*)(xlh + (size_t)srcB * 64 + r * 8);
    int srcC = (sC < hi) ? (int)csr[sC] : d;
    vC = *(const h8*)(xlh + (size_t)srcC * 64 + r * 8);
    int srcD = (sD < hi) ? (int)csr[sD] : d;
    vD = *(const h8*)(xlh + (size_t)srcD * 64 + r * 8);
  }

  int tt = 0;
  for (; tt + 3 < nst; tt += 4) {
    PROC(vA, sA);
    if (tt + 4 < nst) {
      int sN = sA + 16;
      int srcN = (sN < hi) ? (int)csr[sN] : d;
      vA = *(const h8*)(xlh + (size_t)srcN * 64 + r * 8);
    }
    PROC(vB, sB);
    if (tt + 5 < nst) {
      int sN = sB + 16;
      int srcN = (sN < hi) ? (int)csr[sN] : d;
      vB = *(const h8*)(xlh + (size_t)srcN * 64 + r * 8);
    }
    PROC(vC, sC);
    if (tt + 6 < nst) {
      int sN = sC + 16;
      int srcN = (sN < hi) ? (int)csr[sN] : d;
      vC = *(const h8*)(xlh + (size_t)srcN * 64 + r * 8);
    }
    PROC(vD, sD);
    if (tt + 7 < nst) {
      int sN = sD + 16;
      int srcN = (sN < hi) ? (int)csr[sN] : d;
      vD = *(const h8*)(xlh + (size_t)srcN * 64 + r * 8);
    }
    sA += 16; sB += 16; sC += 16; sD += 16;
  }
  {
    const int rem = nst - tt;
    if (rem > 0) PROC(vA, sA);
    if (rem > 1) PROC(vB, sB);
    if (rem > 2) PROC(vC, sC);
  }
#undef PROC

  // merge 4 subgroup partials per half: pure sums (m uniform within half)
#pragma unroll
  for (int off = 8; off <= 16; off <<= 1) {
    ssum += __shfl_xor(ssum, off);
    acc += shfl_xor_h8(acc, off);
  }

  if (g0 && live) {
    const float inv = 1.0f / ssum;
    const float4 bA = *(const float4*)(bias + r * 8);
    const float4 bB = *(const float4*)(bias + r * 8 + 4);
    float4 oA, oB;
    oA.x = fmaxf(fmaf((float)acc[0], inv, bA.x), 0.f);
    oA.y = fmaxf(fmaf((float)acc[1], inv, bA.y), 0.f);
    oA.z = fmaxf(fmaf((float)acc[2], inv, bA.z), 0.f);
    oA.w = fmaxf(fmaf((float)acc[3], inv, bA.w), 0.f);
    oB.x = fmaxf(fmaf((float)acc[4], inv, bB.x), 0.f);
    oB.y = fmaxf(fmaf((float)acc[5], inv, bB.y), 0.f);
    oB.z = fmaxf(fmaf((float)acc[6], inv, bB.z), 0.f);
    oB.w = fmaxf(fmaf((float)acc[7], inv, bB.w), 0.f);
    *(float4*)(out + (size_t)d * 64 + r * 8) = oA;
    *(float4*)(out + (size_t)d * 64 + r * 8 + 4) = oB;
  }
}

extern "C" void kernel_launch(void* const* d_in, const int* in_sizes, int n_in,
                              void* d_out, int out_size, void* d_ws,
                              size_t ws_size, hipStream_t stream) {
  const float* x    = (const float*)d_in[0];
  const float* Wl   = (const float*)d_in[1];
  const float* bl   = (const float*)d_in[2];
  const float* Wr   = (const float*)d_in[3];
  const float* br   = (const float*)d_in[4];
  const float* att  = (const float*)d_in[5];
  const float* bias = (const float*)d_in[6];
  const int* eidx   = (const int*)d_in[7];
  float* out = (float*)d_out;

  const int N = in_sizes[0] / 128;   // 50000 (< 65536 required for packing)
  const int E = in_sizes[7] / 2;     // 800000
  const int NB = (N + 255) >> 8;     // 196 node buckets
  const int nbf = (E + CHUNK - 1) / CHUNK;  // 196 bfill blocks
  const int ntr = (N + 63) / 64;            // 782 transform blocks

  // ---- workspace layout ----
  _Float16* xlh = (_Float16*)d_ws;                    // N*64 f16
  _Float16* xrh = xlh + (size_t)N * 64;               // N*64 f16
  unsigned* pk = (unsigned*)(xrh + (size_t)N * 64);   // NB*CAP u32
  unsigned short* csr = (unsigned short*)(pk + (size_t)NB * CAP);  // NB*CAP u16
  int* bcur    = (int*)(csr + (size_t)NB * CAP);      // NB
  int* rowlo   = bcur + NB;                           // N
  int* rowhi   = rowlo + N;                           // N
  unsigned* nperm = (unsigned*)(rowhi + N);           // NB*128

  hipMemsetAsync(bcur, 0, (size_t)NB * sizeof(int), stream);
  k_tbf<<<nbf + ntr, 256, 0, stream>>>(x, Wl, Wr, bl, br, eidx, bcur, pk, xlh,
                                       xrh, N, E, nbf);
  k_nfill<<<NB, 256, 0, stream>>>(pk, bcur, rowlo, rowhi, csr, nperm, N);
  k_node<<<NB * 32, 256, 0, stream>>>(nperm, rowlo, rowhi, csr, xlh, xrh, att,
                                      bias, out, N);
}

// Round 15
// 66.039 us; speedup vs baseline: 1.2083x; 1.2083x over previous
//
#include <hip/hip_runtime.h>
#include <hip/hip_bf16.h>

#define NEG_SLOPE 0.2f
#define CAP 5120          // per-bucket capacity (avg 4096, ~16-sigma margin)
#define CHUNK 4096        // edges per workgroup in bfill path
#define LOG2E 1.4426950408889634f

typedef __attribute__((ext_vector_type(8))) short short8v;
typedef __attribute__((ext_vector_type(4))) short short4v;
typedef __attribute__((ext_vector_type(4))) float f32x4;
typedef _Float16 __attribute__((ext_vector_type(8))) h8;

__device__ __forceinline__ short f2bf(float f) {
  __hip_bfloat16 b = __float2bfloat16(f);  // RNE
  return *reinterpret_cast<short*>(&b);
}

// f16x8 dot f16x8 accumulated into f32 via v_dot2_f32_f16 (4 instrs).
__device__ __forceinline__ float dot8f(h8 a, h8 b, float c) {
#if __has_builtin(__builtin_amdgcn_fdot2)
  c = __builtin_amdgcn_fdot2(__builtin_shufflevector(a, a, 0, 1),
                             __builtin_shufflevector(b, b, 0, 1), c, false);
  c = __builtin_amdgcn_fdot2(__builtin_shufflevector(a, a, 2, 3),
                             __builtin_shufflevector(b, b, 2, 3), c, false);
  c = __builtin_amdgcn_fdot2(__builtin_shufflevector(a, a, 4, 5),
                             __builtin_shufflevector(b, b, 4, 5), c, false);
  c = __builtin_amdgcn_fdot2(__builtin_shufflevector(a, a, 6, 7),
                             __builtin_shufflevector(b, b, 6, 7), c, false);
#else
#pragma unroll
  for (int i = 0; i < 8; ++i) c += (float)a[i] * (float)b[i];
#endif
  return c;
}

// packed leakyrelu: max(h, 0.2h) elementwise (v_pk_mul + v_pk_max)
__device__ __forceinline__ h8 leaky8(h8 hs) {
  h8 hl = hs * (_Float16)NEG_SLOPE;
  return __builtin_elementwise_max(hs, hl);
}

__device__ __forceinline__ h8 shfl_xor_h8(h8 v, int off) {
  int4 i = *(int4*)&v;
  i.x = __shfl_xor(i.x, off);
  i.y = __shfl_xor(i.y, off);
  i.z = __shfl_xor(i.z, off);
  i.w = __shfl_xor(i.w, off);
  return *(h8*)&i;
}

// 8-lane sum reduction in the VALU pipe via DPP.
__device__ __forceinline__ float row_reduce8(float p) {
  p += __int_as_float(__builtin_amdgcn_update_dpp(
      0, __float_as_int(p), 0xB1, 0xF, 0xF, true));   // quad_perm [1,0,3,2]
  p += __int_as_float(__builtin_amdgcn_update_dpp(
      0, __float_as_int(p), 0x4E, 0xF, 0xF, true));   // quad_perm [2,3,0,1]
  p += __int_as_float(__builtin_amdgcn_update_dpp(
      0, __float_as_int(p), 0x141, 0xF, 0xF, true));  // row_half_mirror
  return p;
}

// K0: Wl||Wr -> W2[128ch][128k] bf16 (B-fragment layout), biasc, zero bcur.
__global__ __launch_bounds__(256) void k_prep(
    const float* __restrict__ Wl, const float* __restrict__ Wr,
    const float* __restrict__ bl, const float* __restrict__ br,
    short* __restrict__ W2, float* __restrict__ biasc,
    int* __restrict__ bcur, int nbk) {
  int idx = blockIdx.x * 256 + threadIdx.x;
  if (idx < 128 * 128) {
    int j = idx >> 7, k = idx & 127;
    float v = (j < 64) ? Wl[j * 128 + k] : Wr[(j - 64) * 128 + k];
    W2[idx] = f2bf(v);
  } else {
    int z = idx - 128 * 128;
    if (z < nbk) bcur[z] = 0;
  }
  if (idx < 128) biasc[idx] = (idx < 64) ? bl[idx] : br[idx - 64];
}

// K1 fused: blocks [0,nbf) = bucketed edge fill; blocks [nbf,..) = LDS-staged
// MFMA transform (W2 bf16 weights). Output restaged through LDS (stride 136 ->
// 272B rows: 16B-aligned, bank-decorrelated) then stored fully coalesced.
__global__ __launch_bounds__(256) void k_tbf(
    const float* __restrict__ x, const short* __restrict__ W2,
    const float* __restrict__ biasc, const int* __restrict__ eidx,
    int* __restrict__ bcur, unsigned* __restrict__ pk,
    _Float16* __restrict__ xlh, _Float16* __restrict__ xrh, int nN, int E_,
    int nbf) {
  __shared__ union {
    struct { int hist[256]; int base[256]; } bf;
    short xs[64 * 136];
  } u;
  const int t = threadIdx.x;

  if (blockIdx.x < nbf) {
    // ---------------- bfill path ----------------
    u.bf.hist[t] = 0;
    __syncthreads();
    const int e0 = blockIdx.x * CHUNK + t * 16;
    unsigned mypk[16];
    int myrank[16];
    const bool valid = (e0 < E_);  // E_ % 16 == 0 -> all-or-nothing per thread
    if (valid) {
      const int4* ps = (const int4*)(eidx + e0);
      const int4* pd = (const int4*)(eidx + E_ + e0);
#pragma unroll
      for (int j = 0; j < 4; ++j) {
        int4 sv = ps[j];
        int4 dv = pd[j];
        int ss[4] = {sv.x, sv.y, sv.z, sv.w};
        int dd[4] = {dv.x, dv.y, dv.z, dv.w};
#pragma unroll
        for (int q = 0; q < 4; ++q) {
          unsigned p = ((unsigned)dd[q] << 16) | (unsigned)ss[q];
          mypk[j * 4 + q] = p;
          myrank[j * 4 + q] = atomicAdd(&u.bf.hist[dd[q] >> 8], 1);
        }
      }
    }
    __syncthreads();
    u.bf.base[t] = u.bf.hist[t] ? atomicAdd(&bcur[t], u.bf.hist[t]) : 0;
    __syncthreads();
    if (valid) {
#pragma unroll
      for (int j = 0; j < 16; ++j) {
        int b = mypk[j] >> 24;
        unsigned idx = (unsigned)(u.bf.base[b] + myrank[j]);
        if (idx < CAP) pk[(unsigned)b * CAP + idx] = mypk[j];
      }
    }
    return;
  }

  // ---------------- transform path ----------------
  const int n0 = (blockIdx.x - nbf) * 64;
#pragma unroll
  for (int i = 0; i < 8; ++i) {
    int f = (i * 256 + t) * 4;        // flat f32 index into 64x128 tile
    int node = f >> 7, k = f & 127;
    int gn = min(n0 + node, nN - 1);
    float4 v = *(const float4*)(x + (size_t)gn * 128 + k);
    short4v s4;
    s4[0] = f2bf(v.x); s4[1] = f2bf(v.y); s4[2] = f2bf(v.z); s4[3] = f2bf(v.w);
    *(short4v*)(u.xs + node * 136 + k) = s4;
  }
  __syncthreads();

  const int w = t >> 6;
  const int lane = t & 63;
  const int r = lane & 15;
  const int kb = lane >> 4;

  short8v bfr[2][4];
#pragma unroll
  for (int c = 0; c < 2; ++c) {
    const short* bp = W2 + (size_t)((w * 2 + c) * 16 + r) * 128 + kb * 8;
#pragma unroll
    for (int kk = 0; kk < 4; ++kk) bfr[c][kk] = *(const short8v*)(bp + kk * 32);
  }

  f32x4 acc[4][2];
#pragma unroll
  for (int nt = 0; nt < 4; ++nt)
#pragma unroll
    for (int c = 0; c < 2; ++c) acc[nt][c] = (f32x4){0.f, 0.f, 0.f, 0.f};

#pragma unroll
  for (int nt = 0; nt < 4; ++nt) {
    short8v afr[4];
#pragma unroll
    for (int kk = 0; kk < 4; ++kk)
      afr[kk] =
          *(const short8v*)(u.xs + (nt * 16 + r) * 136 + kb * 8 + kk * 32);
#pragma unroll
    for (int kk = 0; kk < 4; ++kk) {
      acc[nt][0] =
          __builtin_amdgcn_mfma_f32_16x16x32_bf16(afr[kk], bfr[0][kk],
                                                  acc[nt][0], 0, 0, 0);
      acc[nt][1] =
          __builtin_amdgcn_mfma_f32_16x16x32_bf16(afr[kk], bfr[1][kk],
                                                  acc[nt][1], 0, 0, 0);
    }
  }

  __syncthreads();   // all xs reads complete before output restage
#pragma unroll
  for (int c = 0; c < 2; ++c) {
    const int ch = (w * 2 + c) * 16 + r;
    const float bv = biasc[ch];
#pragma unroll
    for (int nt = 0; nt < 4; ++nt) {
#pragma unroll
      for (int i = 0; i < 4; ++i) {
        int node = nt * 16 + kb * 4 + i;
        _Float16 hv = (_Float16)(acc[nt][c][i] + bv);
        u.xs[node * 136 + ch] = *(short*)&hv;
      }
    }
  }
  __syncthreads();
  // coalesced stores: 2 passes x 16B/thread each for xl and xr halves
#pragma unroll
  for (int p = 0; p < 2; ++p) {
    int e = (p * 256 + t) * 8;        // flat into 64 nodes x 64 ch
    int node = e >> 6, c = e & 63;
    if (n0 + node < nN) {
      short8v sl = *(short8v*)(u.xs + node * 136 + c);
      *(short8v*)((short*)xlh + (size_t)(n0 + node) * 64 + c) = sl;
      short8v sr = *(short8v*)(u.xs + node * 136 + 64 + c);
      *(short8v*)((short*)xrh + (size_t)(n0 + node) * 64 + c) = sr;
    }
  }
}

// K2: per-bucket finalize: node histogram -> scan -> rowlo/rowhi -> 2B csr.
__global__ __launch_bounds__(256) void k_nfill(
    const unsigned* __restrict__ pk, const int* __restrict__ bcur,
    int* __restrict__ rowlo, int* __restrict__ rowhi,
    unsigned short* __restrict__ csr, int nN) {
  __shared__ int hist[256];
  __shared__ int nbase[256];
  __shared__ int wsum[4];
  const int b = blockIdx.x;
  const int t = threadIdx.x;
  const int nb0 = b << 8;
  const int cnt = min(bcur[b], CAP);
  const unsigned gbase = (unsigned)b * CAP;
  hist[t] = 0;
  __syncthreads();
  for (int i = t; i < cnt; i += 256)
    atomicAdd(&hist[(pk[gbase + i] >> 16) & 255], 1);
  __syncthreads();
  const int lane = t & 63;
  const int wid = t >> 6;
  int v = hist[t];
  const int orig = v;
#pragma unroll
  for (int off = 1; off < 64; off <<= 1) {
    int uu = __shfl_up(v, off);
    if (lane >= off) v += uu;
  }
  if (lane == 63) wsum[wid] = v;
  __syncthreads();
  int add = 0;
  for (int ww = 0; ww < wid; ++ww) add += wsum[ww];
  const int excl = v - orig + add;
  nbase[t] = excl;
  if (nb0 + t < nN) {
    rowlo[nb0 + t] = (int)gbase + excl;
    rowhi[nb0 + t] = (int)gbase + excl + orig;
  }
  __syncthreads();
  hist[t] = 0;  // reuse as cursor
  __syncthreads();
  for (int i = t; i < cnt; i += 256) {
    unsigned p = pk[gbase + i];
    int dl = (p >> 16) & 255;
    int slot = nbase[dl] + atomicAdd(&hist[dl], 1);
    csr[gbase + slot] = (unsigned short)(p & 0xFFFFu);
  }
}

// K3: fused per-node online softmax, f16 packed datapath. TWO nodes per wave
// (half-wave each); per node 4 subgroups x 8 lanes; lane r owns ch 8r..8r+7.
// m uniform per half (half-wide max on rare new-max) -> final merge is a pure
// sum. Defer-max fast path: sc == 1 exactly.
__global__ __launch_bounds__(256) void k_node(
    const int* __restrict__ rowlo, const int* __restrict__ rowhi,
    const unsigned short* __restrict__ csr, const _Float16* __restrict__ xlh,
    const _Float16* __restrict__ xrh, const float* __restrict__ att,
    const float* __restrict__ bias, float* __restrict__ out, int nN) {
  const int wvid = (blockIdx.x * 256 + threadIdx.x) >> 6;  // wave id
  const int lane = threadIdx.x & 63;
  const int h = lane >> 5;          // node half 0/1
  const int g = (lane >> 3) & 3;    // subgroup within half, 0..3
  const int r = lane & 7;           // channel block: ch 8r..8r+7
  int d = wvid * 2 + h;
  if (wvid * 2 >= nN) return;
  const bool live = (d < nN);
  d = min(d, nN - 1);

  h8 at8;
#pragma unroll
  for (int i = 0; i < 8; ++i) at8[i] = (_Float16)att[r * 8 + i];

  const h8 xr8 = *(const h8*)(xrh + (size_t)d * 64 + r * 8);
  const h8 sv8 = *(const h8*)(xlh + (size_t)d * 64 + r * 8);

  // self-loop logit (identical across the half's 4 subgroups)
  float ps = dot8f(leaky8(sv8 + xr8), at8, 0.f);
  ps = row_reduce8(ps) * LOG2E;

  const bool g0 = (g == 0);
  float m = ps;                 // uniform per half by construction
  float ssum = g0 ? 1.f : 0.f;
  h8 acc = g0 ? sv8 : (h8){0, 0, 0, 0, 0, 0, 0, 0};

  const int lo = live ? rowlo[d] : 0;
  const int hi = live ? rowhi[d] : 0;
  const int nst = (hi - lo + 3) >> 2;   // rounds of 4 edges per node

#define PROC(VREG, SIDX)                                                      \
  {                                                                           \
    const bool act = ((SIDX) < hi);                                           \
    float p = dot8f(leaky8(VREG + xr8), at8, 0.f);                            \
    p = row_reduce8(p);                                                       \
    const float pm = act ? p * LOG2E : -3.0e38f;                              \
    if (__any(pm > m)) {  /* rare: new max somewhere in the wave */           \
      float q = pm;                                                           \
      q = fmaxf(q, __shfl_xor(q, 8));                                         \
      q = fmaxf(q, __shfl_xor(q, 16));  /* half-wide max */                   \
      const float nm = fmaxf(m, q);     /* uniform per half */                \
      const float sc = exp2f(m - nm);                                         \
      const float w = exp2f(pm - nm);                                         \
      ssum = fmaf(ssum, sc, w);                                               \
      acc = acc * (_Float16)sc + VREG * (_Float16)w;                          \
      m = nm;                                                                 \
    } else {              /* fast path: sc == 1 exactly */                    \
      const float w = exp2f(pm - m);                                          \
      ssum += w;                                                              \
      acc += VREG * (_Float16)w;                                              \
    }                                                                         \
  }

  int sA = lo + g, sB = sA + 4, sC = sA + 8;
  h8 vA, vB, vC;
  {
    int srcA = (sA < hi) ? (int)csr[sA] : d;
    vA = *(const h8*)(xlh + (size_t)srcA * 64 + r * 8);
    int srcB = (sB < hi) ? (int)csr[sB] : d;
    vB = *(const h8*)(xlh + (size_t)srcB * 64 + r * 8);
    int srcC = (sC < hi) ? (int)csr[sC] : d;
    vC = *(const h8*)(xlh + (size_t)srcC * 64 + r * 8);
  }

  int tt = 0;
  for (; tt + 2 < nst; tt += 3) {
    PROC(vA, sA);
    if (tt + 3 < nst) {
      int sN = sA + 12;
      int srcN = (sN < hi) ? (int)csr[sN] : d;
      vA = *(const h8*)(xlh + (size_t)srcN * 64 + r * 8);
    }
    PROC(vB, sB);
    if (tt + 4 < nst) {
      int sN = sB + 12;
      int srcN = (sN < hi) ? (int)csr[sN] : d;
      vB = *(const h8*)(xlh + (size_t)srcN * 64 + r * 8);
    }
    PROC(vC, sC);
    if (tt + 5 < nst) {
      int sN = sC + 12;
      int srcN = (sN < hi) ? (int)csr[sN] : d;
      vC = *(const h8*)(xlh + (size_t)srcN * 64 + r * 8);
    }
    sA += 12; sB += 12; sC += 12;
  }
  {
    const int rem = nst - tt;
    if (rem > 0) PROC(vA, sA);
    if (rem > 1) PROC(vB, sB);
  }
#undef PROC

  // merge 4 subgroup partials per half: pure sums (m uniform within half)
#pragma unroll
  for (int off = 8; off <= 16; off <<= 1) {
    ssum += __shfl_xor(ssum, off);
    acc += shfl_xor_h8(acc, off);
  }

  if (g0 && live) {
    const float inv = 1.0f / ssum;
    const float4 bA = *(const float4*)(bias + r * 8);
    const float4 bB = *(const float4*)(bias + r * 8 + 4);
    float4 oA, oB;
    oA.x = fmaxf(fmaf((float)acc[0], inv, bA.x), 0.f);
    oA.y = fmaxf(fmaf((float)acc[1], inv, bA.y), 0.f);
    oA.z = fmaxf(fmaf((float)acc[2], inv, bA.z), 0.f);
    oA.w = fmaxf(fmaf((float)acc[3], inv, bA.w), 0.f);
    oB.x = fmaxf(fmaf((float)acc[4], inv, bB.x), 0.f);
    oB.y = fmaxf(fmaf((float)acc[5], inv, bB.y), 0.f);
    oB.z = fmaxf(fmaf((float)acc[6], inv, bB.z), 0.f);
    oB.w = fmaxf(fmaf((float)acc[7], inv, bB.w), 0.f);
    *(float4*)(out + (size_t)d * 64 + r * 8) = oA;
    *(float4*)(out + (size_t)d * 64 + r * 8 + 4) = oB;
  }
}

extern "C" void kernel_launch(void* const* d_in, const int* in_sizes, int n_in,
                              void* d_out, int out_size, void* d_ws,
                              size_t ws_size, hipStream_t stream) {
  const float* x    = (const float*)d_in[0];
  const float* Wl   = (const float*)d_in[1];
  const float* bl   = (const float*)d_in[2];
  const float* Wr   = (const float*)d_in[3];
  const float* br   = (const float*)d_in[4];
  const float* att  = (const float*)d_in[5];
  const float* bias = (const float*)d_in[6];
  const int* eidx   = (const int*)d_in[7];
  float* out = (float*)d_out;

  const int N = in_sizes[0] / 128;   // 50000 (< 65536 required for packing)
  const int E = in_sizes[7] / 2;     // 800000
  const int NB = (N + 255) >> 8;     // 196 node buckets
  const int nbf = (E + CHUNK - 1) / CHUNK;  // 196 bfill blocks
  const int ntr = (N + 63) / 64;            // 782 transform blocks

  // ---- workspace layout ----
  _Float16* xlh = (_Float16*)d_ws;                    // N*64 f16
  _Float16* xrh = xlh + (size_t)N * 64;               // N*64 f16
  unsigned* pk = (unsigned*)(xrh + (size_t)N * 64);   // NB*CAP u32
  unsigned short* csr = (unsigned short*)(pk + (size_t)NB * CAP);  // NB*CAP u16
  short* W2    = (short*)(csr + (size_t)NB * CAP);    // 128*128 bf16
  float* biasc = (float*)(W2 + 128 * 128);            // 128 f32
  int* bcur    = (int*)(biasc + 128);                 // NB
  int* rowlo   = bcur + NB;                           // N
  int* rowhi   = rowlo + N;                           // N

  k_prep<<<(128 * 128 + NB + 255) / 256, 256, 0, stream>>>(
      Wl, Wr, bl, br, W2, biasc, bcur, NB);
  k_tbf<<<nbf + ntr, 256, 0, stream>>>(x, W2, biasc, eidx, bcur, pk, xlh, xrh,
                                       N, E, nbf);
  k_nfill<<<NB, 256, 0, stream>>>(pk, bcur, rowlo, rowhi, csr, N);
  {
    int waves = (N + 1) / 2;
    k_node<<<(waves + 3) / 4, 256, 0, stream>>>(rowlo, rowhi, csr, xlh, xrh,
                                                att, bias, out, N);
  }
}